// Round 1
// 1127.278 us; speedup vs baseline: 1.1048x; 1.1048x over previous
//
#include <hip/hip_runtime.h>
#include <hip/hip_bf16.h>
#include <stdint.h>

typedef __attribute__((ext_vector_type(8))) short short8;
typedef __attribute__((ext_vector_type(4))) float f32x4;

__device__ __forceinline__ float b2f(short s) {
    union { unsigned u; float f; } v; v.u = ((unsigned)(unsigned short)s) << 16; return v.f;
}
__device__ __forceinline__ short f2b(float f) {
    union { float f; unsigned u; } v; v.f = f;
    unsigned r = (v.u + 0x7FFF + ((v.u >> 16) & 1)) >> 16;
    return (short)r;
}

// async global->LDS, 16B per lane. LDS dest is wave-uniform base + lane*16.
__device__ __forceinline__ void gload16(const void* g, void* l) {
    __builtin_amdgcn_global_load_lds(
        (const __attribute__((address_space(1))) void*)(uintptr_t)g,
        (__attribute__((address_space(3))) void*)(uintptr_t)l,
        16, 0, 0);
}

#define BAR()    asm volatile("s_barrier" ::: "memory")
#define WAITV2() asm volatile("s_waitcnt vmcnt(2)" ::: "memory")
#define WAITV0() asm volatile("s_waitcnt vmcnt(0)" ::: "memory")
#define WAITL0() asm volatile("s_waitcnt lgkmcnt(0)" ::: "memory")

// ---------------- cast fp32 -> bf16 (8 elems/thread) ----------------
__global__ __launch_bounds__(256) void cast_bf16_kernel(
    const float* __restrict__ src, short* __restrict__ dst, int n8) {
    int i = blockIdx.x * 256 + threadIdx.x;
    if (i >= n8) return;
    const float4* s = (const float4*)src + (size_t)i * 2;
    float4 x0 = s[0], x1 = s[1];
    short8 o;
    o[0] = f2b(x0.x); o[1] = f2b(x0.y); o[2] = f2b(x0.z); o[3] = f2b(x0.w);
    o[4] = f2b(x1.x); o[5] = f2b(x1.y); o[6] = f2b(x1.z); o[7] = f2b(x1.w);
    *((short8*)dst + i) = o;
}

// ---------- transpose-cast W[K,N] f32 -> Wt[N,K] bf16 (8 k per thread) ----------
__global__ __launch_bounds__(256) void transpose_cast_kernel(
    const float* __restrict__ W, short* __restrict__ Wt, int K, int N, int total) {
    int t = blockIdx.x * 256 + threadIdx.x;
    if (t >= total) return;
    const float* src = W + (size_t)blockIdx.y * K * N;
    short* dst = Wt + (size_t)blockIdx.y * K * N;
    int n = t % N;
    int k0 = (t / N) * 8;
    short8 o;
#pragma unroll
    for (int i = 0; i < 8; i++) o[i] = f2b(src[(size_t)(k0 + i) * N + n]);
    *(short8*)(dst + (size_t)n * K + k0) = o;
}

// ---------- repack We2[16][256][32] f32 -> Bt2[32][4096] bf16 (Bt2[a][e*256+h]) ----------
__global__ __launch_bounds__(256) void repack_We2_kernel(
    const float* __restrict__ We2, short* __restrict__ Bt2) {
    int t = blockIdx.x * 256 + threadIdx.x;      // 16384 threads: (e, a, h0/8)
    int h0 = (t & 31) * 8;
    int a = (t >> 5) & 31;
    int e = t >> 10;
    short8 o;
#pragma unroll
    for (int j = 0; j < 8; j++) o[j] = f2b(We2[((size_t)e * 256 + h0 + j) * 32 + a]);
    *(short8*)(Bt2 + (size_t)a * 4096 + e * 256 + h0) = o;
}

// ---------------- generic C = relu(A @ Bt^T + bias), bf16 out ----------------
// (kept for selector layer1 only: N=128)
__global__ __launch_bounds__(256, 3)
void gemm_bt_bias_relu(const short* __restrict__ A, const short* __restrict__ Bt,
                       const float* __restrict__ bias, short* __restrict__ C,
                       int M, int N, int K) {
    __shared__ __align__(16) short As[128 * 32];
    __shared__ __align__(16) short Bs[128 * 32];
    const int tid = threadIdx.x;
    const int w = tid >> 6, lane = tid & 63;
    const int tm = blockIdx.y * 128, tn = blockIdx.x * 128;
    const int wm = (w & 1) * 64, wn = (w >> 1) * 64;
    const int r = lane & 15, q = lane >> 4, qk = q * 8;

    const int c0 = w * 2, c1 = w * 2 + 1;
    const int srow0 = c0 * 16 + (lane >> 2);
    const int srow1 = c1 * 16 + (lane >> 2);
    const int skk = (lane & 3) * 8;
    const short* gA0 = A + (size_t)(tm + srow0) * K + skk;
    const short* gA1 = A + (size_t)(tm + srow1) * K + skk;
    const short* gB0 = Bt + (size_t)(tn + srow0) * K + skk;
    const short* gB1 = Bt + (size_t)(tn + srow1) * K + skk;
    short* lA0 = &As[c0 * 512]; short* lA1 = &As[c1 * 512];
    short* lB0 = &Bs[c0 * 512]; short* lB1 = &Bs[c1 * 512];

    f32x4 acc[4][4] = {};
    for (int k0 = 0; k0 < K; k0 += 32) {
        gload16(gA0 + k0, lA0);
        gload16(gA1 + k0, lA1);
        gload16(gB0 + k0, lB0);
        gload16(gB1 + k0, lB1);
        __syncthreads();
        short8 a[4], b[4];
#pragma unroll
        for (int i = 0; i < 4; i++) a[i] = *(const short8*)&As[(wm + i * 16 + r) * 32 + qk];
#pragma unroll
        for (int j = 0; j < 4; j++) b[j] = *(const short8*)&Bs[(wn + j * 16 + r) * 32 + qk];
#pragma unroll
        for (int i = 0; i < 4; i++)
#pragma unroll
            for (int j = 0; j < 4; j++)
                acc[i][j] = __builtin_amdgcn_mfma_f32_16x16x32_bf16(a[i], b[j], acc[i][j], 0, 0, 0);
        __syncthreads();
    }
#pragma unroll
    for (int j = 0; j < 4; j++) {
        int col = tn + wn + j * 16 + r;
        float bj = bias[col];
#pragma unroll
        for (int i = 0; i < 4; i++)
#pragma unroll
            for (int rr = 0; rr < 4; rr++) {
                int row = tm + wm + i * 16 + q * 4 + rr;
                float v = fmaxf(acc[i][j][rr] + bj, 0.f);
                C[(size_t)row * N + col] = f2b(v);
            }
    }
}

// ---------------- selector last layer + softmax ----------------
__global__ __launch_bounds__(256)
void selector_softmax(const short* __restrict__ s1, const short* __restrict__ Ws2t,
                      const float* __restrict__ bs2, float* __restrict__ wsel) {
    int tid = threadIdx.x;
    int row = blockIdx.x * 16 + (tid >> 4);
    int e = tid & 15;
    const short8* a = (const short8*)(s1 + (size_t)row * 128);
    const short8* b = (const short8*)(Ws2t + (size_t)e * 128);
    float acc = bs2[e];
#pragma unroll
    for (int kk = 0; kk < 16; ++kk) {
        short8 av = a[kk], bv = b[kk];
#pragma unroll
        for (int i = 0; i < 8; i++) acc = fmaf(b2f(av[i]), b2f(bv[i]), acc);
    }
    float m = acc;
#pragma unroll
    for (int off = 8; off >= 1; off >>= 1) m = fmaxf(m, __shfl_xor(m, off, 16));
    float ex = __expf(acc - m);
    float s = ex;
#pragma unroll
    for (int off = 8; off >= 1; off >>= 1) s += __shfl_xor(s, off, 16);
    wsel[(size_t)row * 16 + e] = ex / s;
}

// ================= 256x256 8-phase GEMM (T2+T3+T4+T5) =================
// C = post(A @ Bt^T + bias), A[M,K] bf16, Bt[N,K] bf16.
// MODE 0: C = bf16(relu(acc+bias))
// MODE 1: C = bf16(relu(acc+bias) * wselp[row*16 + tn>>8])   (expert-scaled eh)
// 8 waves (2Mx4N), BK=64, LDS 128KiB (2 buf x (A:2x16KB + B:2x16KB)).
// Swizzle: byte ^= (row&7)<<4 (G4), applied via pre-swizzled global source
// (gload_lds writes linearly) + swizzled ds_read addresses.
template<int MODE>
__global__ __launch_bounds__(512, 2)
void gemm256(const short* __restrict__ A, const short* __restrict__ Bt,
             const float* __restrict__ bias, const float* __restrict__ wselp,
             short* __restrict__ C, int M, int N, int K) {
    extern __shared__ __align__(16) short lds[];
    const int tid = threadIdx.x;
    const int w = tid >> 6, lane = tid & 63;
    const int wr = w >> 2, wc = w & 3;

    // bijective XCD swizzle (nwg % 8 == 0 for all our launches)
    const int gx = gridDim.x;
    const int b = blockIdx.y * gx + blockIdx.x;
    const int per = (gx * gridDim.y) >> 3;
    const int sb = (b & 7) * per + (b >> 3);
    const int bx = sb % gx, by = sb / gx;
    const int tm = by * 256, tn = bx * 256;

    // --- staging (per-lane source addr incl. inverse swizzle) ---
    const int rih = w * 8 + (lane >> 3);                 // row within half (+ i*64)
    const int colel = (((lane & 7) ^ (lane >> 3)) << 3); // swizzled source col (elems)
    const short* pA = A + (size_t)(tm + rih) * K + colel;
    const short* pB = Bt + (size_t)(tn + rih) * K + colel;
    const size_t rK64 = (size_t)64 * K, rK128 = (size_t)128 * K;
    short* const ldsw = lds + w * 512;   // wave slice of each half-region

    // STG dest layout (shorts): buf*32768 + [B?16384] + h*8192 + i*4096 + w*512
#define STG_A(buf, h, t) do { \
        const short* s_ = pA + (size_t)(h) * rK128 + (size_t)(t) * 64; \
        short* d_ = ldsw + (buf) * 32768 + (h) * 8192; \
        gload16(s_, d_); \
        gload16(s_ + rK64, d_ + 4096); } while (0)
#define STG_B(buf, h, t) do { \
        const short* s_ = pB + (size_t)(h) * rK128 + (size_t)(t) * 64; \
        short* d_ = ldsw + (buf) * 32768 + 16384 + (h) * 8192; \
        gload16(s_, d_); \
        gload16(s_ + rK64, d_ + 4096); } while (0)

    // --- ds_read addressing (byte offsets, swizzled) ---
    const int rA = lane & 15;
    const int csw0 = (((lane >> 4) << 4)) ^ ((lane & 7) << 4);
    const int csw1 = (64 + ((lane >> 4) << 4)) ^ ((lane & 7) << 4);
    const char* const ldsB_ = (const char*)lds;
    const int aBase0 = wr * 16384 + rA * 128;                        // A half = wr
    const int bBase0 = 32768 + (wc >> 1) * 16384 + ((wc & 1) * 64 + rA) * 128;

    f32x4 acc[8][4] = {};
    short8 a[4][2], b0[2][2], b1[2][2];
    const int nt = K >> 6;

    // prologue: tile0 fully + tile1.A0 (10 loads); allow last 2 in flight
    STG_A(0, 0, 0); STG_A(0, 1, 0); STG_B(0, 0, 0); STG_B(0, 1, 0);
    STG_A(1, 0, 1);
    WAITV2(); BAR();

    for (int t = 0; t < nt; ++t) {
        const int cur = t & 1, nxt = cur ^ 1;
        const char* pa = ldsB_ + cur * 65536 + aBase0;
        const char* pb = ldsB_ + cur * 65536 + bBase0;
        // ---- phase 1: read a(lo)+b0 ; stage A1(t+1) ; quad (lo,lo) ----
#pragma unroll
        for (int m = 0; m < 4; m++) {
            a[m][0] = *(const short8*)(pa + m * 2048 + csw0);
            a[m][1] = *(const short8*)(pa + m * 2048 + csw1);
        }
#pragma unroll
        for (int n = 0; n < 2; n++) {
            b0[n][0] = *(const short8*)(pb + n * 2048 + csw0);
            b0[n][1] = *(const short8*)(pb + n * 2048 + csw1);
        }
        if (t + 1 < nt) STG_A(nxt, 1, t + 1);
        BAR(); WAITL0(); __builtin_amdgcn_sched_barrier(0);
        __builtin_amdgcn_s_setprio(1);
#pragma unroll
        for (int m = 0; m < 4; m++)
#pragma unroll
            for (int n = 0; n < 2; n++) {
                acc[m][n] = __builtin_amdgcn_mfma_f32_16x16x32_bf16(a[m][0], b0[n][0], acc[m][n], 0, 0, 0);
                acc[m][n] = __builtin_amdgcn_mfma_f32_16x16x32_bf16(a[m][1], b0[n][1], acc[m][n], 0, 0, 0);
            }
        __builtin_amdgcn_s_setprio(0);
        BAR();
        // ---- phase 2: read b1 ; stage B0(t+1) ; quad (lo,hi) ----
#pragma unroll
        for (int n = 0; n < 2; n++) {
            b1[n][0] = *(const short8*)(pb + (2 + n) * 2048 + csw0);
            b1[n][1] = *(const short8*)(pb + (2 + n) * 2048 + csw1);
        }
        if (t + 1 < nt) STG_B(nxt, 0, t + 1);
        BAR(); WAITL0(); __builtin_amdgcn_sched_barrier(0);
        __builtin_amdgcn_s_setprio(1);
#pragma unroll
        for (int m = 0; m < 4; m++)
#pragma unroll
            for (int n = 0; n < 2; n++) {
                acc[m][2 + n] = __builtin_amdgcn_mfma_f32_16x16x32_bf16(a[m][0], b1[n][0], acc[m][2 + n], 0, 0, 0);
                acc[m][2 + n] = __builtin_amdgcn_mfma_f32_16x16x32_bf16(a[m][1], b1[n][1], acc[m][2 + n], 0, 0, 0);
            }
        __builtin_amdgcn_s_setprio(0);
        BAR();
        // ---- phase 3: read a(hi) ; stage B1(t+1) ; quad (hi,hi) ----
#pragma unroll
        for (int m = 0; m < 4; m++) {
            a[m][0] = *(const short8*)(pa + (4 + m) * 2048 + csw0);
            a[m][1] = *(const short8*)(pa + (4 + m) * 2048 + csw1);
        }
        if (t + 1 < nt) STG_B(nxt, 1, t + 1);
        BAR(); WAITL0(); __builtin_amdgcn_sched_barrier(0);
        __builtin_amdgcn_s_setprio(1);
#pragma unroll
        for (int m = 0; m < 4; m++)
#pragma unroll
            for (int n = 0; n < 2; n++) {
                acc[4 + m][2 + n] = __builtin_amdgcn_mfma_f32_16x16x32_bf16(a[m][0], b1[n][0], acc[4 + m][2 + n], 0, 0, 0);
                acc[4 + m][2 + n] = __builtin_amdgcn_mfma_f32_16x16x32_bf16(a[m][1], b1[n][1], acc[4 + m][2 + n], 0, 0, 0);
            }
        __builtin_amdgcn_s_setprio(0);
        BAR();
        // ---- phase 4: no reads ; stage A0(t+2) into cur ; counted vmcnt ; quad (hi,lo) ----
        if (t + 2 < nt) { STG_A(cur, 0, t + 2); WAITV2(); }
        else { WAITV0(); }
        BAR();
        __builtin_amdgcn_s_setprio(1);
#pragma unroll
        for (int m = 0; m < 4; m++)
#pragma unroll
            for (int n = 0; n < 2; n++) {
                acc[4 + m][n] = __builtin_amdgcn_mfma_f32_16x16x32_bf16(a[m][0], b0[n][0], acc[4 + m][n], 0, 0, 0);
                acc[4 + m][n] = __builtin_amdgcn_mfma_f32_16x16x32_bf16(a[m][1], b0[n][1], acc[4 + m][n], 0, 0, 0);
            }
        __builtin_amdgcn_s_setprio(0);
        BAR();
    }
#undef STG_A
#undef STG_B

    // ---- epilogue ----
    float biasv[4];
#pragma unroll
    for (int n = 0; n < 4; n++) biasv[n] = bias[tn + wc * 64 + n * 16 + rA];
    const int q4 = (lane >> 4) * 4;
#pragma unroll
    for (int m = 0; m < 8; m++)
#pragma unroll
        for (int rr = 0; rr < 4; rr++) {
            const int row = tm + wr * 128 + m * 16 + q4 + rr;
            float ws = 1.f;
            if (MODE == 1) ws = wselp[(size_t)row * 16 + (tn >> 8)];
#pragma unroll
            for (int n = 0; n < 4; n++) {
                const int col = tn + wc * 64 + n * 16 + rA;
                float v = fmaxf(acc[m][n][rr] + biasv[n], 0.f);
                if (MODE == 1) v *= ws;
                C[(size_t)row * N + col] = f2b(v);
            }
        }
}

// ================= skinny fused GEMM2: out (+)= s_eh @ Bt2 (+ wsel@be2) =================
// s_eh[B,2048] bf16 (one 8-expert group), Bt2 base (row stride 4096) [32][2048 used].
// 4 waves x 128 rows/block, 2-phase double-buffered LDS staging.
__global__ __launch_bounds__(256)
void fuse_gemm(const short* __restrict__ Aeh, const short* __restrict__ Bt2,
               const float* __restrict__ wsel, const float* __restrict__ be2,
               float* __restrict__ out, int accflag) {
    __shared__ __align__(16) short sA[2][128 * 64];
    const int tid = threadIdx.x;
    const int w = tid >> 6, lane = tid & 63;
    const int tm = blockIdx.x * 128;
    const int rih = w * 8 + (lane >> 3);
    const int colel = (((lane & 7) ^ (lane >> 3)) << 3);
    const short* pA = Aeh + (size_t)(tm + rih) * 2048 + colel;
    const int rA = lane & 15;
    const int csw0 = (((lane >> 4) << 4)) ^ ((lane & 7) << 4);
    const int csw1 = (64 + ((lane >> 4) << 4)) ^ ((lane & 7) << 4);
    const short* pBg = Bt2 + (size_t)rA * 4096 + ((lane >> 4) << 3);

    f32x4 acc[2][2] = {};
#define STG_E(buf, t) do { \
        const short* s_ = pA + (size_t)(t) * 64; \
        short* d_ = &sA[buf][w * 512]; \
        gload16(s_, d_); \
        gload16(s_ + (size_t)32 * 2048, d_ + 2048); \
        gload16(s_ + (size_t)64 * 2048, d_ + 4096); \
        gload16(s_ + (size_t)96 * 2048, d_ + 6144); } while (0)

    const int NT = 32;          // 2048 / 64
    STG_E(0, 0);
    WAITV0(); BAR();
    for (int t = 0; t < NT; ++t) {
        const int cur = t & 1;
        if (t + 1 < NT) STG_E(cur ^ 1, t + 1);
        const char* pa = (const char*)&sA[cur][0] + (w * 32 + rA) * 128;
        short8 av[2][2], bv[2][2];
#pragma unroll
        for (int m = 0; m < 2; m++) {
            av[m][0] = *(const short8*)(pa + m * 2048 + csw0);
            av[m][1] = *(const short8*)(pa + m * 2048 + csw1);
        }
#pragma unroll
        for (int n = 0; n < 2; n++) {
            bv[n][0] = *(const short8*)(pBg + (size_t)n * 16 * 4096 + t * 64);
            bv[n][1] = *(const short8*)(pBg + (size_t)n * 16 * 4096 + t * 64 + 32);
        }
#pragma unroll
        for (int m = 0; m < 2; m++)
#pragma unroll
            for (int n = 0; n < 2; n++) {
                acc[m][n] = __builtin_amdgcn_mfma_f32_16x16x32_bf16(av[m][0], bv[n][0], acc[m][n], 0, 0, 0);
                acc[m][n] = __builtin_amdgcn_mfma_f32_16x16x32_bf16(av[m][1], bv[n][1], acc[m][n], 0, 0, 0);
            }
        WAITL0(); WAITV0(); BAR();
    }
#undef STG_E

    float be2v0[16], be2v1[16];
    if (!accflag) {
#pragma unroll
        for (int e = 0; e < 16; e++) {
            be2v0[e] = be2[e * 32 + rA];
            be2v1[e] = be2[e * 32 + 16 + rA];
        }
    }
    const int q4 = (lane >> 4) * 4;
#pragma unroll
    for (int m = 0; m < 2; m++)
#pragma unroll
        for (int rr = 0; rr < 4; rr++) {
            const int row = tm + w * 32 + m * 16 + q4 + rr;
            float v0 = acc[m][0][rr], v1 = acc[m][1][rr];
            if (!accflag) {
#pragma unroll
                for (int e = 0; e < 16; e++) {
                    float wv = wsel[(size_t)row * 16 + e];
                    v0 = fmaf(wv, be2v0[e], v0);
                    v1 = fmaf(wv, be2v1[e], v1);
                }
                out[(size_t)row * 32 + rA] = v0;
                out[(size_t)row * 32 + 16 + rA] = v1;
            } else {
                out[(size_t)row * 32 + rA] += v0;
                out[(size_t)row * 32 + 16 + rA] += v1;
            }
        }
}

extern "C" void kernel_launch(void* const* d_in, const int* in_sizes, int n_in,
                              void* d_out, int out_size, void* d_ws, size_t ws_size,
                              hipStream_t stream) {
    const float* obs = (const float*)d_in[0];
    const float* Wb0 = (const float*)d_in[1]; const float* bb0 = (const float*)d_in[2];
    const float* Wb1 = (const float*)d_in[3]; const float* bb1 = (const float*)d_in[4];
    const float* Wb2 = (const float*)d_in[5]; const float* bb2 = (const float*)d_in[6];
    const float* We1 = (const float*)d_in[7]; const float* be1 = (const float*)d_in[8];
    const float* We2 = (const float*)d_in[9]; const float* be2 = (const float*)d_in[10];
    const float* Ws0 = (const float*)d_in[11]; const float* bs0 = (const float*)d_in[12];
    const float* Ws1 = (const float*)d_in[13]; const float* bs1 = (const float*)d_in[14];
    const float* Ws2 = (const float*)d_in[15]; const float* bs2 = (const float*)d_in[16];

    const int B = 65536;
    char* ws = (char*)d_ws;
    size_t off = 0;
    auto alloc = [&](size_t bytes) { void* p = ws + off; off += (bytes + 255) & ~(size_t)255; return p; };
    short* obs_bf = (short*)alloc((size_t)B * 512 * 2);
    short* h1     = (short*)alloc((size_t)B * 1024 * 2);   // also reused as s_eh (with h2)
    short* h2     = (short*)alloc((size_t)B * 1024 * 2);
    short* hbuf   = (short*)alloc((size_t)B * 512 * 2);
    short* s0     = (short*)alloc((size_t)B * 256 * 2);
    short* s1     = (short*)alloc((size_t)B * 128 * 2);
    float* wsel   = (float*)alloc((size_t)B * 16 * 4);
    short* Wb0t   = (short*)alloc((size_t)512 * 1024 * 2);
    short* Wb1t   = (short*)alloc((size_t)1024 * 1024 * 2);
    short* Wb2t   = (short*)alloc((size_t)1024 * 512 * 2);
    short* We1t   = (short*)alloc((size_t)16 * 512 * 256 * 2);
    short* Ws0t   = (short*)alloc((size_t)512 * 256 * 2);
    short* Ws1t   = (short*)alloc((size_t)256 * 128 * 2);
    short* Ws2t   = (short*)alloc((size_t)128 * 16 * 2);
    short* Bt2    = (short*)alloc((size_t)32 * 4096 * 2);
    // scaled eh for one 8-expert group: B x 2048 bf16 = 256 MB, aliases h1+h2
    short* s_eh = h1;

    static int inited = 0;
    if (!inited) {
        hipFuncSetAttribute(reinterpret_cast<const void*>(gemm256<0>),
                            hipFuncAttributeMaxDynamicSharedMemorySize, 131072);
        hipFuncSetAttribute(reinterpret_cast<const void*>(gemm256<1>),
                            hipFuncAttributeMaxDynamicSharedMemorySize, 131072);
        inited = 1;
    }

    // --- preprocessing: casts / transposes / repack ---
    cast_bf16_kernel<<<(B * 512 / 8 + 255) / 256, 256, 0, stream>>>(obs, obs_bf, B * 512 / 8);
    transpose_cast_kernel<<<dim3((1024 * 512 / 8 + 255) / 256, 1), 256, 0, stream>>>(Wb0, Wb0t, 512, 1024, 1024 * 512 / 8);
    transpose_cast_kernel<<<dim3((1024 * 1024 / 8 + 255) / 256, 1), 256, 0, stream>>>(Wb1, Wb1t, 1024, 1024, 1024 * 1024 / 8);
    transpose_cast_kernel<<<dim3((512 * 1024 / 8 + 255) / 256, 1), 256, 0, stream>>>(Wb2, Wb2t, 1024, 512, 512 * 1024 / 8);
    transpose_cast_kernel<<<dim3((256 * 512 / 8 + 255) / 256, 16), 256, 0, stream>>>(We1, We1t, 512, 256, 256 * 512 / 8);
    transpose_cast_kernel<<<dim3((256 * 512 / 8 + 255) / 256, 1), 256, 0, stream>>>(Ws0, Ws0t, 512, 256, 256 * 512 / 8);
    transpose_cast_kernel<<<dim3((128 * 256 / 8 + 255) / 256, 1), 256, 0, stream>>>(Ws1, Ws1t, 256, 128, 128 * 256 / 8);
    transpose_cast_kernel<<<dim3((16 * 128 / 8 + 255) / 256, 1), 256, 0, stream>>>(Ws2, Ws2t, 128, 16, 16 * 128 / 8);
    repack_We2_kernel<<<64, 256, 0, stream>>>(We2, Bt2);

    // --- selector chain ---
    gemm256<0><<<dim3(1, B / 256), 512, 131072, stream>>>(obs_bf, Ws0t, bs0, nullptr, s0, B, 256, 512);
    gemm_bt_bias_relu<<<dim3(1, B / 128), 256, 0, stream>>>(s0, Ws1t, bs1, s1, B, 128, 256);
    selector_softmax<<<B / 16, 256, 0, stream>>>(s1, Ws2t, bs2, wsel);

    // --- backbone ---
    gemm256<0><<<dim3(4, B / 256), 512, 131072, stream>>>(obs_bf, Wb0t, bb0, nullptr, h1, B, 1024, 512);
    gemm256<0><<<dim3(4, B / 256), 512, 131072, stream>>>(h1, Wb1t, bb1, nullptr, h2, B, 1024, 1024);
    gemm256<0><<<dim3(2, B / 256), 512, 131072, stream>>>(h2, Wb2t, bb2, nullptr, hbuf, B, 512, 1024);

    // --- experts: 2 groups of 8 experts; eh big-GEMM (wsel folded) + skinny fuse ---
    for (int g = 0; g < 2; ++g) {
        gemm256<1><<<dim3(8, B / 256), 512, 131072, stream>>>(
            hbuf, We1t + (size_t)g * 8 * 256 * 512, be1 + g * 2048, wsel + g * 8,
            s_eh, B, 2048, 512);
        fuse_gemm<<<B / 128, 256, 0, stream>>>(
            s_eh, Bt2 + g * 2048, wsel, be2, (float*)d_out, g);
    }
}